// Round 15
// baseline (153.304 us; speedup 1.0000x reference)
//
#include <hip/hip_runtime.h>

// ---------------------------------------------------------------------------
// MultiHeadAttention  B=2,S=4096,D=512,H=8,dk=64 — bf16 MFMA pipeline.
//   0) convert_w: Wq,Wk,Wv,Wo f32 -> bf16 once
//   1) gemm_proj3 (grid.z=3): dbuf+prefetch+fused-barrier pipeline (R13)
//   2) attn_kernel: 8 waves x 16 q-rows, KV tile 128, static-max softmax,
//      l via ones-row MFMA, and NEW: cross-tile pipelining — QK(t+1) MFMAs
//      interleaved with softmax(t) VALU/trans work (2 barriers/tile,
//      ping-pong score arrays sA/sB with static indexing).
//   3) gemm_out (64x128 tile): dbuf pipeline -> fp32 out
// ---------------------------------------------------------------------------

#define DM   512
#define NH   8
#define DK   64
#define SEQ  4096
#define BATCH 2
#define MROWS (BATCH*SEQ)
#define KVT  128                    // keys per tile
#define CSC  0.18033688011112042f   // log2(e)/sqrt(64)
#define MBIAS 12.0f                 // static softmax bias (exp2 domain)

typedef __attribute__((ext_vector_type(4))) float  f32x4;
typedef __attribute__((ext_vector_type(8))) short  s16x8;
typedef __attribute__((ext_vector_type(4))) short  s16x4;
typedef __attribute__((ext_vector_type(4))) unsigned short u16x4;
typedef __attribute__((ext_vector_type(4))) int    i32x4;
typedef __attribute__((ext_vector_type(2))) int    i32x2;

static __device__ __forceinline__ unsigned short f2bf(float f) {
    union { float f; unsigned int u; } a; a.f = f;
    unsigned int r = a.u + 0x7FFFu + ((a.u >> 16) & 1u);   // RNE
    return (unsigned short)(r >> 16);
}
static __device__ __forceinline__ int cvtpk(float lo, float hi) {
    int r;
    asm("v_cvt_pk_bf16_f32 %0, %1, %2" : "=v"(r) : "v"(lo), "v"(hi));
    return r;
}
static __device__ __forceinline__ float fexp2(float x) {
    float r;
    asm("v_exp_f32 %0, %1" : "=v"(r) : "v"(x));
    return r;
}
// Safe ONLY with DISTINCT a/b values (two live registers). permlane*_swap(x,x)
// on one SSA value can degenerate to an in-place row permutation (R6/R7 bug).
static __device__ __forceinline__ void swap32(int &a, int &b) {
    auto t = __builtin_amdgcn_permlane32_swap(a, b, false, false);
    a = t[0]; b = t[1];
}
static __device__ __forceinline__ void swap16(int &a, int &b) {
    auto t = __builtin_amdgcn_permlane16_swap(a, b, false, false);
    a = t[0]; b = t[1];
}

// ---------------------------------------------------------------------------
// Weight pre-conversion: 4 x (512x512) f32 -> bf16.
// ---------------------------------------------------------------------------
__global__ __launch_bounds__(256)
void convert_w(const float* __restrict__ W0, const float* __restrict__ W1,
               const float* __restrict__ W2, const float* __restrict__ W3,
               unsigned short* __restrict__ O)
{
    const int idx   = blockIdx.x * 256 + threadIdx.x;   // 131072 threads
    const int which = idx >> 15;                        // 32768 chunks per W
    const int off   = (idx & 32767) * 8;
    const float* W = (which == 0) ? W0 : (which == 1) ? W1 : (which == 2) ? W2 : W3;
    f32x4 a = *(const f32x4*)(W + off);
    f32x4 b = *(const f32x4*)(W + off + 4);
    i32x4 pk;
    pk[0] = cvtpk(a[0], a[1]); pk[1] = cvtpk(a[2], a[3]);
    pk[2] = cvtpk(b[0], b[1]); pk[3] = cvtpk(b[2], b[3]);
    *(i32x4*)(O + (size_t)which * (DM * DM) + off) = pk;
}

// ---------------------------------------------------------------------------
// Fused input projections: z=0 Q (pre-scaled CSC), z=1 K, z=2 V (transposed).
// 128x128 tile, BK=32, 4 waves 2x2. Double-buffered LDS + reg-prefetch +
// ONE fused {lgkmcnt(0); s_barrier} per k-step.  (Frozen R13.)
// ---------------------------------------------------------------------------
__global__ __launch_bounds__(256)
void gemm_proj3(const float* __restrict__ a0, const float* __restrict__ a1,
                const float* __restrict__ a2,
                const unsigned short* __restrict__ Wb,   // 3 x DM*DM bf16
                const float* __restrict__ b0, const float* __restrict__ b1,
                const float* __restrict__ b2,
                unsigned short* __restrict__ O0, unsigned short* __restrict__ O1,
                unsigned short* __restrict__ O2)
{
    __shared__ short As[2][128 * 40];
    __shared__ short Bs[2][128 * 40];

    const int z = blockIdx.z;
    const float* A   = (z == 0) ? a0 : (z == 1) ? a1 : a2;
    const short* W   = (const short*)Wb + (size_t)z * DM * DM;
    const float* bias= (z == 0) ? b0 : (z == 1) ? b1 : b2;
    unsigned short* O= (z == 0) ? O0 : (z == 1) ? O1 : O2;
    const float oscale = (z == 0) ? CSC : 1.0f;
    const bool  vt = (z == 2);

    const int tid  = threadIdx.x;
    const int lane = tid & 63;
    const int wid  = tid >> 6;
    const int g = lane >> 4, r = lane & 15;
    const int wm = wid >> 1, wn = wid & 1;
    const int brow = blockIdx.x * 128;
    const int bcol = blockIdx.y * 128;

    const float* agp[4]; int alw[4];
    #pragma unroll
    for (int j = 0; j < 4; ++j) {
        int c = tid + 256 * j;
        int row = c >> 3, cc = c & 7;
        agp[j] = A + (size_t)(brow + row) * DM + cc * 4;
        alw[j] = row * 40 + cc * 4;
    }
    const short* wgp[2]; int wlw[2];
    #pragma unroll
    for (int j = 0; j < 2; ++j) {
        int c = tid + 256 * j;
        int row = c >> 2, cc = c & 3;
        wgp[j] = W + (size_t)(bcol + row) * DM + cc * 8;
        wlw[j] = row * 40 + cc * 8;
    }

    f32x4 acc[4][4];
    #pragma unroll
    for (int i = 0; i < 4; ++i)
        #pragma unroll
        for (int j = 0; j < 4; ++j) acc[i][j] = (f32x4)(0.0f);

    f32x4 ar[4]; s16x8 wr[2];
    #pragma unroll
    for (int j = 0; j < 4; ++j) ar[j] = *(const f32x4*)(agp[j]);
    #pragma unroll
    for (int j = 0; j < 2; ++j) wr[j] = *(const s16x8*)(wgp[j]);

    int cur = 0;
    for (int k0 = 0; k0 < DM; k0 += 32) {
        short* as = As[cur];
        short* bs = Bs[cur];
        #pragma unroll
        for (int j = 0; j < 4; ++j) {
            i32x2 pk;
            pk[0] = cvtpk(ar[j][0], ar[j][1]);
            pk[1] = cvtpk(ar[j][2], ar[j][3]);
            *(i32x2*)(&as[alw[j]]) = pk;
        }
        #pragma unroll
        for (int j = 0; j < 2; ++j) *(s16x8*)(&bs[wlw[j]]) = wr[j];
        if (k0 + 32 < DM) {
            #pragma unroll
            for (int j = 0; j < 4; ++j) ar[j] = *(const f32x4*)(agp[j] + k0 + 32);
            #pragma unroll
            for (int j = 0; j < 2; ++j) wr[j] = *(const s16x8*)(wgp[j] + k0 + 32);
        }
        asm volatile("s_waitcnt lgkmcnt(0)\n\ts_barrier" ::: "memory");
        __builtin_amdgcn_sched_barrier(0);

        s16x8 af[4], bfr[4];
        #pragma unroll
        for (int mf = 0; mf < 4; ++mf)
            af[mf] = *(const s16x8*)(&as[(wm * 64 + mf * 16 + r) * 40 + g * 8]);
        #pragma unroll
        for (int nf = 0; nf < 4; ++nf)
            bfr[nf] = *(const s16x8*)(&bs[(wn * 64 + nf * 16 + r) * 40 + g * 8]);
        #pragma unroll
        for (int mf = 0; mf < 4; ++mf)
            #pragma unroll
            for (int nf = 0; nf < 4; ++nf)
                acc[mf][nf] = __builtin_amdgcn_mfma_f32_16x16x32_bf16(
                    af[mf], bfr[nf], acc[mf][nf], 0, 0, 0);
        cur ^= 1;
    }

    const int ncolbase = bcol + wn * 64;
    const int mrowbase = brow + wm * 64;
    #pragma unroll
    for (int mf = 0; mf < 4; ++mf) {
        #pragma unroll
        for (int nf = 0; nf < 4; ++nf) {
            const int ncol = ncolbase + nf * 16 + r;
            const int m0   = mrowbase + mf * 16 + g * 4;
            const float bv = bias[ncol];
            const int h = ncol >> 6, d = ncol & 63;
            if (!vt) {
                #pragma unroll
                for (int i = 0; i < 4; ++i) {
                    int m = m0 + i;
                    int b = m >> 12, s = m & (SEQ - 1);
                    O[((size_t)(b * NH + h) * SEQ + s) * DK + d] =
                        f2bf((acc[mf][nf][i] + bv) * oscale);
                }
            } else {
                const int b = m0 >> 12, s0 = m0 & (SEQ - 1);
                u16x4 pk;
                #pragma unroll
                for (int i = 0; i < 4; ++i) pk[i] = f2bf(acc[mf][nf][i] + bv);
                *(u16x4*)(&O[((size_t)(b * NH + h) * DK + d) * SEQ + s0]) = pk;
            }
        }
    }
}

// ---------------------------------------------------------------------------
// Output projection: 64x128 tile, dbuf + prefetch + single-barrier pipeline.
// ---------------------------------------------------------------------------
__global__ __launch_bounds__(256)
void gemm_out(const unsigned short* __restrict__ Ctx,
              const unsigned short* __restrict__ Wb,
              const float* __restrict__ bias,
              float* __restrict__ O)
{
    __shared__ short As[2][64 * 40];
    __shared__ short Bs[2][128 * 40];

    const int tid  = threadIdx.x;
    const int lane = tid & 63;
    const int wid  = tid >> 6;
    const int g = lane >> 4, r = lane & 15;
    const int wm = wid >> 1, wn = wid & 1;
    const int brow = blockIdx.x * 64;
    const int bcol = blockIdx.y * 128;
    const short* W = (const short*)Wb;

    const short* agp; int alw;
    {
        int row = tid >> 2, cc = tid & 3;
        agp = (const short*)Ctx + (size_t)(brow + row) * DM + cc * 8;
        alw = row * 40 + cc * 8;
    }
    const short* wgp[2]; int wlw[2];
    #pragma unroll
    for (int j = 0; j < 2; ++j) {
        int c = tid + 256 * j;
        int row = c >> 2, cc = c & 3;
        wgp[j] = W + (size_t)(bcol + row) * DM + cc * 8;
        wlw[j] = row * 40 + cc * 8;
    }

    f32x4 acc[2][4];
    #pragma unroll
    for (int i = 0; i < 2; ++i)
        #pragma unroll
        for (int j = 0; j < 4; ++j) acc[i][j] = (f32x4)(0.0f);

    s16x8 ar; s16x8 wr[2];
    ar = *(const s16x8*)agp;
    #pragma unroll
    for (int j = 0; j < 2; ++j) wr[j] = *(const s16x8*)(wgp[j]);

    int cur = 0;
    for (int k0 = 0; k0 < DM; k0 += 32) {
        short* as = As[cur];
        short* bs = Bs[cur];
        *(s16x8*)(&as[alw]) = ar;
        #pragma unroll
        for (int j = 0; j < 2; ++j) *(s16x8*)(&bs[wlw[j]]) = wr[j];
        if (k0 + 32 < DM) {
            ar = *(const s16x8*)(agp + k0 + 32);
            #pragma unroll
            for (int j = 0; j < 2; ++j) wr[j] = *(const s16x8*)(wgp[j] + k0 + 32);
        }
        asm volatile("s_waitcnt lgkmcnt(0)\n\ts_barrier" ::: "memory");
        __builtin_amdgcn_sched_barrier(0);

        s16x8 af[2], bfr[4];
        #pragma unroll
        for (int mf = 0; mf < 2; ++mf)
            af[mf] = *(const s16x8*)(&as[(wm * 32 + mf * 16 + r) * 40 + g * 8]);
        #pragma unroll
        for (int nf = 0; nf < 4; ++nf)
            bfr[nf] = *(const s16x8*)(&bs[(wn * 64 + nf * 16 + r) * 40 + g * 8]);
        #pragma unroll
        for (int mf = 0; mf < 2; ++mf)
            #pragma unroll
            for (int nf = 0; nf < 4; ++nf)
                acc[mf][nf] = __builtin_amdgcn_mfma_f32_16x16x32_bf16(
                    af[mf], bfr[nf], acc[mf][nf], 0, 0, 0);
        cur ^= 1;
    }

    const int ncolbase = bcol + wn * 64;
    const int mrowbase = brow + wm * 32;
    #pragma unroll
    for (int mf = 0; mf < 2; ++mf) {
        #pragma unroll
        for (int nf = 0; nf < 4; ++nf) {
            const int ncol = ncolbase + nf * 16 + r;
            const int m0   = mrowbase + mf * 16 + g * 4;
            const float bv = bias[ncol];
            #pragma unroll
            for (int i = 0; i < 4; ++i)
                O[(size_t)(m0 + i) * DM + ncol] = acc[mf][nf][i] + bv;
        }
    }
}

// ---------------------------------------------------------------------------
// Flash attention, cross-tile pipelined: 8 waves x 16 q-rows, KV tile 128.
//   S^T  = mfma(A=K[t,d],  B=Q[q,d])  -> C[t,q], col(lane&15)=q
//   ctx^T= mfma(A=Vt[d,t], B=P[q,t])  -> C[d,q], col(lane&15)=q
// Per tile: {stage(t+1); bar; exp(t) INTERLEAVED with QK(t+1) MFMAs;
// pack(t); PV(t); bar}. QK(t+1) reads the other dbuf half -> zero data
// dependence on softmax(t): trans/VALU and MFMA pipes dovetail within a wave
// (fixes R13/R14's barrier-lockstep phase alignment). Ping-pong sA/sB with
// static indexing (rule #20). Second barrier protects V(t) reads from
// write(t+2) (verified race). Static-max softmax; l via ones-row MFMA.
// ---------------------------------------------------------------------------
__global__ __launch_bounds__(512, 2)
void attn_kernel(const unsigned short* __restrict__ Qw,
                 const unsigned short* __restrict__ Kw,
                 const unsigned short* __restrict__ Vtw,
                 unsigned short* __restrict__ Ctx)
{
    __shared__ short Kbuf[2][KVT * 64];
    __shared__ short Vbuf[2][64 * KVT];

    const int tid  = threadIdx.x;
    const int lane = tid & 63;
    const int wid  = tid >> 6;            // 0..7
    const int g = lane >> 4, r = lane & 15;

    const int B   = blockIdx.x;            // 0..511
    const int xcd = B & 7;
    const int j   = B >> 3;                // 0..63
    const int bh  = xcd * 2 + (j >> 5);    // 2 bh per XCD
    const int qt  = j & 31;
    const int q0  = qt * 128 + wid * 16;   // wave owns 16 q-rows

    const short* Qp = (const short*)Qw  + (size_t)bh * SEQ * DK;
    const short* Kp = (const short*)Kw  + (size_t)bh * SEQ * DK;
    const short* Vp = (const short*)Vtw + (size_t)bh * DK * SEQ;

    s16x8 qfr[2];
    #pragma unroll
    for (int df = 0; df < 2; ++df)
        qfr[df] = *(const s16x8*)(Qp + (size_t)(q0 + r) * DK + df * 32 + g * 8);

    s16x8 ones;
    #pragma unroll
    for (int i = 0; i < 8; ++i) ones[i] = (short)0x3F80;

    f32x4 o[4];
    #pragma unroll
    for (int df = 0; df < 4; ++df) o[df] = (f32x4)(0.0f);
    f32x4 l_acc = (f32x4)(0.0f);

    // staging: K 1024 chunks (16B), V 1024 chunks; 2 rounds of 512 threads
    int    lwk[2], lwv[2];
    size_t kgo[2], vgo[2];
    #pragma unroll
    for (int jj = 0; jj < 2; ++jj) {
        int c = tid + 512 * jj;
        int krow = c >> 3, kcc = c & 7;
        kgo[jj] = (size_t)krow * DK + kcc * 8;
        lwk[jj] = krow * 64 + ((kcc ^ (krow & 7)) * 8);
        int vrow = c >> 4, vcc = c & 15;
        vgo[jj] = (size_t)vrow * SEQ + vcc * 8;
        lwv[jj] = vrow * KVT + ((vcc ^ (vrow & 15)) * 8);
    }

    // ---- prologue: tile0 -> buf0; issue tile1 loads; QK(0) -> sA ----
    s16x8 kr[2], vr[2];
    #pragma unroll
    for (int jj = 0; jj < 2; ++jj) {
        kr[jj] = *(const s16x8*)(Kp + kgo[jj]);
        vr[jj] = *(const s16x8*)(Vp + vgo[jj]);
    }
    #pragma unroll
    for (int jj = 0; jj < 2; ++jj) {
        *(s16x8*)(&Kbuf[0][lwk[jj]]) = kr[jj];
        *(s16x8*)(&Vbuf[0][lwv[jj]]) = vr[jj];
    }
    #pragma unroll
    for (int jj = 0; jj < 2; ++jj) {
        kr[jj] = *(const s16x8*)(Kp + (size_t)KVT * DK + kgo[jj]);
        vr[jj] = *(const s16x8*)(Vp + vgo[jj] + KVT);
    }
    asm volatile("s_waitcnt lgkmcnt(0)\n\ts_barrier" ::: "memory");
    __builtin_amdgcn_sched_barrier(0);

    f32x4 sA[8], sB[8];
    #pragma unroll
    for (int tf = 0; tf < 8; ++tf) sA[tf] = (f32x4)(-MBIAS);
    #pragma unroll
    for (int tf = 0; tf < 8; ++tf) {
        const short* krow = &Kbuf[0][(tf * 16 + r) * 64];
        s16x8 ka0 = *(const s16x8*)(krow + ((g ^ (r & 7)) * 8));
        s16x8 ka1 = *(const s16x8*)(krow + (((4 | g) ^ (r & 7)) * 8));
        sA[tf] = __builtin_amdgcn_mfma_f32_16x16x32_bf16(ka0, qfr[0], sA[tf], 0, 0, 0);
        sA[tf] = __builtin_amdgcn_mfma_f32_16x16x32_bf16(ka1, qfr[1], sA[tf], 0, 0, 0);
    }

#define ATT_BODY(T0, CUR, SCUR, SNXT)                                          \
  {                                                                            \
    const bool hasNext = (T0) + KVT < SEQ;                                     \
    if (hasNext) {                                                             \
        short* kbw = Kbuf[(CUR) ^ 1];                                          \
        short* vbw = Vbuf[(CUR) ^ 1];                                          \
        _Pragma("unroll")                                                      \
        for (int jj = 0; jj < 2; ++jj) {                                       \
            *(s16x8*)(&kbw[lwk[jj]]) = kr[jj];                                 \
            *(s16x8*)(&vbw[lwv[jj]]) = vr[jj];                                 \
        }                                                                      \
        if ((T0) + 2 * KVT < SEQ) {                                            \
            _Pragma("unroll")                                                  \
            for (int jj = 0; jj < 2; ++jj) {                                   \
                kr[jj] = *(const s16x8*)(Kp + (size_t)((T0) + 2 * KVT) * DK + kgo[jj]); \
                vr[jj] = *(const s16x8*)(Vp + vgo[jj] + (T0) + 2 * KVT);       \
            }                                                                  \
        }                                                                      \
    }                                                                          \
    asm volatile("s_waitcnt lgkmcnt(0)\n\ts_barrier" ::: "memory");            \
    __builtin_amdgcn_sched_barrier(0);                                         \
    /* softmax(t) [trans/VALU]  ||  QK(t+1) [MFMA, other buffer] */            \
    _Pragma("unroll")                                                          \
    for (int tf = 0; tf < 8; ++tf) SNXT[tf] = (f32x4)(-MBIAS);                 \
    const short* kbN = Kbuf[(CUR) ^ 1];                                        \
    _Pragma("unroll")                                                          \
    for (int tf = 0; tf < 8; ++tf) {                                           \
        SCUR[tf][0] = fexp2(SCUR[tf][0]);                                      \
        SCUR[tf][1] = fexp2(SCUR[tf][1]);                                      \
        SCUR[tf][2] = fexp2(SCUR[tf][2]);                                      \
        SCUR[tf][3] = fexp2(SCUR[tf][3]);                                      \
        if (hasNext) {                                                         \
            const short* krow = &kbN[(tf * 16 + r) * 64];                      \
            s16x8 ka0 = *(const s16x8*)(krow + ((g ^ (r & 7)) * 8));           \
            s16x8 ka1 = *(const s16x8*)(krow + (((4 | g) ^ (r & 7)) * 8));     \
            SNXT[tf] = __builtin_amdgcn_mfma_f32_16x16x32_bf16(ka0, qfr[0], SNXT[tf], 0, 0, 0); \
            SNXT[tf] = __builtin_amdgcn_mfma_f32_16x16x32_bf16(ka1, qfr[1], SNXT[tf], 0, 0, 0); \
        }                                                                      \
    }                                                                          \
    /* pack(t) */                                                              \
    s16x8 pb[4];                                                               \
    _Pragma("unroll")                                                          \
    for (int h = 0; h < 4; ++h) {                                              \
        int A0 = cvtpk(SCUR[2 * h][0],     SCUR[2 * h][1]);                    \
        int A1 = cvtpk(SCUR[2 * h][2],     SCUR[2 * h][3]);                    \
        int A2 = cvtpk(SCUR[2 * h + 1][0], SCUR[2 * h + 1][1]);                \
        int A3 = cvtpk(SCUR[2 * h + 1][2], SCUR[2 * h + 1][3]);                \
        swap32(A0, A2); swap16(A0, A2);                                        \
        swap32(A1, A3); swap16(A1, A3);                                        \
        i32x4 w; w[0] = A0; w[1] = A1; w[2] = A2; w[3] = A3;                   \
        pb[h] = __builtin_bit_cast(s16x8, w);                                  \
    }                                                                          \
    /* PV(t) + l(t) */                                                         \
    const short* vbC = Vbuf[CUR];                                              \
    __builtin_amdgcn_s_setprio(1);                                             \
    _Pragma("unroll")                                                          \
    for (int h = 0; h < 4; ++h)                                                \
        l_acc = __builtin_amdgcn_mfma_f32_16x16x32_bf16(ones, pb[h], l_acc, 0, 0, 0); \
    _Pragma("unroll")                                                          \
    for (int df = 0; df < 4; ++df) {                                           \
        const short* vrow = &vbC[(df * 16 + r) * KVT];                         \
        _Pragma("unroll")                                                      \
        for (int h = 0; h < 4; ++h) {                                          \
            s16x8 va = *(const s16x8*)(vrow + (((h * 4 + g) ^ r) * 8));        \
            o[df] = __builtin_amdgcn_mfma_f32_16x16x32_bf16(va, pb[h], o[df], 0, 0, 0); \
        }                                                                      \
    }                                                                          \
    __builtin_amdgcn_s_setprio(0);                                             \
    asm volatile("s_waitcnt lgkmcnt(0)\n\ts_barrier" ::: "memory");            \
    __builtin_amdgcn_sched_barrier(0);                                         \
  }

    for (int t0 = 0; t0 < SEQ; t0 += 2 * KVT) {
        ATT_BODY(t0,        0, sA, sB)
        ATT_BODY(t0 + KVT,  1, sB, sA)
    }
#undef ATT_BODY

    // ---- epilogue: l lane-local in l_acc[0] ----
    const int b = bh >> 3, h2 = bh & 7;
    {
        const float inv = 1.0f / l_acc[0];
        const int q = q0 + r;
        const size_t rowoff = (size_t)(b * SEQ + q) * DM + h2 * DK;
        #pragma unroll
        for (int df = 0; df < 4; ++df) {
            u16x4 pk;
            #pragma unroll
            for (int i = 0; i < 4; ++i) pk[i] = f2bf(o[df][i] * inv);
            *(u16x4*)(&Ctx[rowoff + df * 16 + g * 4]) = pk;
        }
    }
}

// ---------------------------------------------------------------------------
extern "C" void kernel_launch(void* const* d_in, const int* in_sizes, int n_in,
                              void* d_out, int out_size, void* d_ws, size_t ws_size,
                              hipStream_t stream)
{
    const float* q  = (const float*)d_in[0];
    const float* k  = (const float*)d_in[1];
    const float* v  = (const float*)d_in[2];
    const float* Wq = (const float*)d_in[3];
    const float* bq = (const float*)d_in[4];
    const float* Wk = (const float*)d_in[5];
    const float* bk = (const float*)d_in[6];
    const float* Wv = (const float*)d_in[7];
    const float* bv = (const float*)d_in[8];
    const float* Wo = (const float*)d_in[9];
    const float* bo = (const float*)d_in[10];

    const size_t NE = (size_t)MROWS * DM;            // 4.19M elems per buffer
    unsigned short* ws  = (unsigned short*)d_ws;
    unsigned short* Qw  = ws;                        // [B,H,S,64] bf16, pre-scaled
    unsigned short* Kw  = Qw  + NE;                  // [B,H,S,64] bf16
    unsigned short* Vtw = Kw  + NE;                  // [B,H,64,S] bf16
    unsigned short* Ctx = Vtw + NE;                  // [B*S, 512] bf16
    unsigned short* Wb  = Ctx + NE;                  // 4 x [512,512] bf16

    convert_w<<<512, 256, 0, stream>>>(Wq, Wk, Wv, Wo, Wb);
    dim3 gg3(MROWS / 128, DM / 128, 3);              // (64, 4, 3) = 768 blocks
    gemm_proj3<<<gg3, 256, 0, stream>>>(q, k, v, Wb, bq, bk, bv, Qw, Kw, Vtw);
    attn_kernel<<<512, 512, 0, stream>>>(Qw, Kw, Vtw, Ctx);
    dim3 ggo(MROWS / 64, DM / 128);                  // (128, 4) = 512 blocks
    gemm_out<<<ggo, 256, 0, stream>>>(Ctx, Wb + (size_t)3 * DM * DM, bo, (float*)d_out);
}

// Round 16
// 148.754 us; speedup vs baseline: 1.0306x; 1.0306x over previous
//
#include <hip/hip_runtime.h>

// ---------------------------------------------------------------------------
// MultiHeadAttention  B=2,S=4096,D=512,H=8,dk=64 — bf16 MFMA pipeline.
//   0) convert_w: Wq,Wk,Wv,Wo f32 -> bf16 once
//   1) gemm_proj3 (grid.z=3): dbuf+prefetch+fused-barrier pipeline (R13)
//   2) attn_kernel: 8 waves x 16 q-rows, KV tile 64 (32KB LDS -> 4 blocks/CU
//      = 32 waves/CU, 2x R13's TLP; independent blocks break barrier
//      lockstep), static-max softmax (MBIAS in acc init), l via ones-row
//      MFMA, dbuf + reg-prefetch + fused lgkmcnt+barrier.
//   3) gemm_out (64x128 tile): dbuf pipeline -> fp32 out
// ---------------------------------------------------------------------------

#define DM   512
#define NH   8
#define DK   64
#define SEQ  4096
#define BATCH 2
#define MROWS (BATCH*SEQ)
#define KVT  64                     // keys per tile (32KB LDS dbuf)
#define CSC  0.18033688011112042f   // log2(e)/sqrt(64)
#define MBIAS 12.0f                 // static softmax bias (exp2 domain)

typedef __attribute__((ext_vector_type(4))) float  f32x4;
typedef __attribute__((ext_vector_type(8))) short  s16x8;
typedef __attribute__((ext_vector_type(4))) short  s16x4;
typedef __attribute__((ext_vector_type(4))) unsigned short u16x4;
typedef __attribute__((ext_vector_type(4))) int    i32x4;
typedef __attribute__((ext_vector_type(2))) int    i32x2;

static __device__ __forceinline__ unsigned short f2bf(float f) {
    union { float f; unsigned int u; } a; a.f = f;
    unsigned int r = a.u + 0x7FFFu + ((a.u >> 16) & 1u);   // RNE
    return (unsigned short)(r >> 16);
}
static __device__ __forceinline__ int cvtpk(float lo, float hi) {
    int r;
    asm("v_cvt_pk_bf16_f32 %0, %1, %2" : "=v"(r) : "v"(lo), "v"(hi));
    return r;
}
static __device__ __forceinline__ float fexp2(float x) {
    float r;
    asm("v_exp_f32 %0, %1" : "=v"(r) : "v"(x));
    return r;
}
// Safe ONLY with DISTINCT a/b values (two live registers). permlane*_swap(x,x)
// on one SSA value can degenerate to an in-place row permutation (R6/R7 bug).
static __device__ __forceinline__ void swap32(int &a, int &b) {
    auto t = __builtin_amdgcn_permlane32_swap(a, b, false, false);
    a = t[0]; b = t[1];
}
static __device__ __forceinline__ void swap16(int &a, int &b) {
    auto t = __builtin_amdgcn_permlane16_swap(a, b, false, false);
    a = t[0]; b = t[1];
}

// ---------------------------------------------------------------------------
// Weight pre-conversion: 4 x (512x512) f32 -> bf16.
// ---------------------------------------------------------------------------
__global__ __launch_bounds__(256)
void convert_w(const float* __restrict__ W0, const float* __restrict__ W1,
               const float* __restrict__ W2, const float* __restrict__ W3,
               unsigned short* __restrict__ O)
{
    const int idx   = blockIdx.x * 256 + threadIdx.x;   // 131072 threads
    const int which = idx >> 15;                        // 32768 chunks per W
    const int off   = (idx & 32767) * 8;
    const float* W = (which == 0) ? W0 : (which == 1) ? W1 : (which == 2) ? W2 : W3;
    f32x4 a = *(const f32x4*)(W + off);
    f32x4 b = *(const f32x4*)(W + off + 4);
    i32x4 pk;
    pk[0] = cvtpk(a[0], a[1]); pk[1] = cvtpk(a[2], a[3]);
    pk[2] = cvtpk(b[0], b[1]); pk[3] = cvtpk(b[2], b[3]);
    *(i32x4*)(O + (size_t)which * (DM * DM) + off) = pk;
}

// ---------------------------------------------------------------------------
// Fused input projections: z=0 Q (pre-scaled CSC), z=1 K, z=2 V (transposed).
// 128x128 tile, BK=32, 4 waves 2x2. Double-buffered LDS + reg-prefetch +
// ONE fused {lgkmcnt(0); s_barrier} per k-step.  (Frozen R13.)
// ---------------------------------------------------------------------------
__global__ __launch_bounds__(256)
void gemm_proj3(const float* __restrict__ a0, const float* __restrict__ a1,
                const float* __restrict__ a2,
                const unsigned short* __restrict__ Wb,   // 3 x DM*DM bf16
                const float* __restrict__ b0, const float* __restrict__ b1,
                const float* __restrict__ b2,
                unsigned short* __restrict__ O0, unsigned short* __restrict__ O1,
                unsigned short* __restrict__ O2)
{
    __shared__ short As[2][128 * 40];
    __shared__ short Bs[2][128 * 40];

    const int z = blockIdx.z;
    const float* A   = (z == 0) ? a0 : (z == 1) ? a1 : a2;
    const short* W   = (const short*)Wb + (size_t)z * DM * DM;
    const float* bias= (z == 0) ? b0 : (z == 1) ? b1 : b2;
    unsigned short* O= (z == 0) ? O0 : (z == 1) ? O1 : O2;
    const float oscale = (z == 0) ? CSC : 1.0f;
    const bool  vt = (z == 2);

    const int tid  = threadIdx.x;
    const int lane = tid & 63;
    const int wid  = tid >> 6;
    const int g = lane >> 4, r = lane & 15;
    const int wm = wid >> 1, wn = wid & 1;
    const int brow = blockIdx.x * 128;
    const int bcol = blockIdx.y * 128;

    const float* agp[4]; int alw[4];
    #pragma unroll
    for (int j = 0; j < 4; ++j) {
        int c = tid + 256 * j;
        int row = c >> 3, cc = c & 7;
        agp[j] = A + (size_t)(brow + row) * DM + cc * 4;
        alw[j] = row * 40 + cc * 4;
    }
    const short* wgp[2]; int wlw[2];
    #pragma unroll
    for (int j = 0; j < 2; ++j) {
        int c = tid + 256 * j;
        int row = c >> 2, cc = c & 3;
        wgp[j] = W + (size_t)(bcol + row) * DM + cc * 8;
        wlw[j] = row * 40 + cc * 8;
    }

    f32x4 acc[4][4];
    #pragma unroll
    for (int i = 0; i < 4; ++i)
        #pragma unroll
        for (int j = 0; j < 4; ++j) acc[i][j] = (f32x4)(0.0f);

    f32x4 ar[4]; s16x8 wr[2];
    #pragma unroll
    for (int j = 0; j < 4; ++j) ar[j] = *(const f32x4*)(agp[j]);
    #pragma unroll
    for (int j = 0; j < 2; ++j) wr[j] = *(const s16x8*)(wgp[j]);

    int cur = 0;
    for (int k0 = 0; k0 < DM; k0 += 32) {
        short* as = As[cur];
        short* bs = Bs[cur];
        #pragma unroll
        for (int j = 0; j < 4; ++j) {
            i32x2 pk;
            pk[0] = cvtpk(ar[j][0], ar[j][1]);
            pk[1] = cvtpk(ar[j][2], ar[j][3]);
            *(i32x2*)(&as[alw[j]]) = pk;
        }
        #pragma unroll
        for (int j = 0; j < 2; ++j) *(s16x8*)(&bs[wlw[j]]) = wr[j];
        if (k0 + 32 < DM) {
            #pragma unroll
            for (int j = 0; j < 4; ++j) ar[j] = *(const f32x4*)(agp[j] + k0 + 32);
            #pragma unroll
            for (int j = 0; j < 2; ++j) wr[j] = *(const s16x8*)(wgp[j] + k0 + 32);
        }
        asm volatile("s_waitcnt lgkmcnt(0)\n\ts_barrier" ::: "memory");
        __builtin_amdgcn_sched_barrier(0);

        s16x8 af[4], bfr[4];
        #pragma unroll
        for (int mf = 0; mf < 4; ++mf)
            af[mf] = *(const s16x8*)(&as[(wm * 64 + mf * 16 + r) * 40 + g * 8]);
        #pragma unroll
        for (int nf = 0; nf < 4; ++nf)
            bfr[nf] = *(const s16x8*)(&bs[(wn * 64 + nf * 16 + r) * 40 + g * 8]);
        #pragma unroll
        for (int mf = 0; mf < 4; ++mf)
            #pragma unroll
            for (int nf = 0; nf < 4; ++nf)
                acc[mf][nf] = __builtin_amdgcn_mfma_f32_16x16x32_bf16(
                    af[mf], bfr[nf], acc[mf][nf], 0, 0, 0);
        cur ^= 1;
    }

    const int ncolbase = bcol + wn * 64;
    const int mrowbase = brow + wm * 64;
    #pragma unroll
    for (int mf = 0; mf < 4; ++mf) {
        #pragma unroll
        for (int nf = 0; nf < 4; ++nf) {
            const int ncol = ncolbase + nf * 16 + r;
            const int m0   = mrowbase + mf * 16 + g * 4;
            const float bv = bias[ncol];
            const int h = ncol >> 6, d = ncol & 63;
            if (!vt) {
                #pragma unroll
                for (int i = 0; i < 4; ++i) {
                    int m = m0 + i;
                    int b = m >> 12, s = m & (SEQ - 1);
                    O[((size_t)(b * NH + h) * SEQ + s) * DK + d] =
                        f2bf((acc[mf][nf][i] + bv) * oscale);
                }
            } else {
                const int b = m0 >> 12, s0 = m0 & (SEQ - 1);
                u16x4 pk;
                #pragma unroll
                for (int i = 0; i < 4; ++i) pk[i] = f2bf(acc[mf][nf][i] + bv);
                *(u16x4*)(&O[((size_t)(b * NH + h) * DK + d) * SEQ + s0]) = pk;
            }
        }
    }
}

// ---------------------------------------------------------------------------
// Output projection: 64x128 tile, dbuf + prefetch + single-barrier pipeline.
// ---------------------------------------------------------------------------
__global__ __launch_bounds__(256)
void gemm_out(const unsigned short* __restrict__ Ctx,
              const unsigned short* __restrict__ Wb,
              const float* __restrict__ bias,
              float* __restrict__ O)
{
    __shared__ short As[2][64 * 40];
    __shared__ short Bs[2][128 * 40];

    const int tid  = threadIdx.x;
    const int lane = tid & 63;
    const int wid  = tid >> 6;
    const int g = lane >> 4, r = lane & 15;
    const int wm = wid >> 1, wn = wid & 1;
    const int brow = blockIdx.x * 64;
    const int bcol = blockIdx.y * 128;
    const short* W = (const short*)Wb;

    const short* agp; int alw;
    {
        int row = tid >> 2, cc = tid & 3;
        agp = (const short*)Ctx + (size_t)(brow + row) * DM + cc * 8;
        alw = row * 40 + cc * 8;
    }
    const short* wgp[2]; int wlw[2];
    #pragma unroll
    for (int j = 0; j < 2; ++j) {
        int c = tid + 256 * j;
        int row = c >> 2, cc = c & 3;
        wgp[j] = W + (size_t)(bcol + row) * DM + cc * 8;
        wlw[j] = row * 40 + cc * 8;
    }

    f32x4 acc[2][4];
    #pragma unroll
    for (int i = 0; i < 2; ++i)
        #pragma unroll
        for (int j = 0; j < 4; ++j) acc[i][j] = (f32x4)(0.0f);

    s16x8 ar; s16x8 wr[2];
    ar = *(const s16x8*)agp;
    #pragma unroll
    for (int j = 0; j < 2; ++j) wr[j] = *(const s16x8*)(wgp[j]);

    int cur = 0;
    for (int k0 = 0; k0 < DM; k0 += 32) {
        short* as = As[cur];
        short* bs = Bs[cur];
        *(s16x8*)(&as[alw]) = ar;
        #pragma unroll
        for (int j = 0; j < 2; ++j) *(s16x8*)(&bs[wlw[j]]) = wr[j];
        if (k0 + 32 < DM) {
            ar = *(const s16x8*)(agp + k0 + 32);
            #pragma unroll
            for (int j = 0; j < 2; ++j) wr[j] = *(const s16x8*)(wgp[j] + k0 + 32);
        }
        asm volatile("s_waitcnt lgkmcnt(0)\n\ts_barrier" ::: "memory");
        __builtin_amdgcn_sched_barrier(0);

        s16x8 af[2], bfr[4];
        #pragma unroll
        for (int mf = 0; mf < 2; ++mf)
            af[mf] = *(const s16x8*)(&as[(wm * 32 + mf * 16 + r) * 40 + g * 8]);
        #pragma unroll
        for (int nf = 0; nf < 4; ++nf)
            bfr[nf] = *(const s16x8*)(&bs[(wn * 64 + nf * 16 + r) * 40 + g * 8]);
        #pragma unroll
        for (int mf = 0; mf < 2; ++mf)
            #pragma unroll
            for (int nf = 0; nf < 4; ++nf)
                acc[mf][nf] = __builtin_amdgcn_mfma_f32_16x16x32_bf16(
                    af[mf], bfr[nf], acc[mf][nf], 0, 0, 0);
        cur ^= 1;
    }

    const int ncolbase = bcol + wn * 64;
    const int mrowbase = brow + wm * 32;
    #pragma unroll
    for (int mf = 0; mf < 2; ++mf) {
        #pragma unroll
        for (int nf = 0; nf < 4; ++nf) {
            const int ncol = ncolbase + nf * 16 + r;
            const int m0   = mrowbase + mf * 16 + g * 4;
            const float bv = bias[ncol];
            #pragma unroll
            for (int i = 0; i < 4; ++i)
                O[(size_t)(m0 + i) * DM + ncol] = acc[mf][nf][i] + bv;
        }
    }
}

// ---------------------------------------------------------------------------
// Flash attention: 8 waves x 16 q-rows (512 thr), KV tile 64, swapped orient.
//   S^T  = mfma(A=K[t,d],  B=Q[q,d])  -> C[t,q], col(lane&15)=q
//   ctx^T= mfma(A=Vt[d,t], B=P[q,t])  -> C[d,q], col(lane&15)=q
// KVT=64 -> 32KB LDS dbuf -> 4 blocks/CU = 32 waves/CU (2x R13's TLP;
// independent blocks break barrier lockstep). Static-max softmax (MBIAS in
// acc init); l via ones-row MFMA. Dbuf + reg-prefetch + fused barrier.
// ---------------------------------------------------------------------------
__global__ __launch_bounds__(512, 8)
void attn_kernel(const unsigned short* __restrict__ Qw,
                 const unsigned short* __restrict__ Kw,
                 const unsigned short* __restrict__ Vtw,
                 unsigned short* __restrict__ Ctx)
{
    __shared__ short Kbuf[2][KVT * 64];
    __shared__ short Vbuf[2][64 * KVT];

    const int tid  = threadIdx.x;
    const int lane = tid & 63;
    const int wid  = tid >> 6;            // 0..7
    const int g = lane >> 4, r = lane & 15;

    const int B   = blockIdx.x;            // 0..511
    const int xcd = B & 7;
    const int j   = B >> 3;                // 0..63
    const int bh  = xcd * 2 + (j >> 5);    // 2 bh per XCD
    const int qt  = j & 31;
    const int q0  = qt * 128 + wid * 16;   // wave owns 16 q-rows

    const short* Qp = (const short*)Qw  + (size_t)bh * SEQ * DK;
    const short* Kp = (const short*)Kw  + (size_t)bh * SEQ * DK;
    const short* Vp = (const short*)Vtw + (size_t)bh * DK * SEQ;

    s16x8 qfr[2];
    #pragma unroll
    for (int df = 0; df < 2; ++df)
        qfr[df] = *(const s16x8*)(Qp + (size_t)(q0 + r) * DK + df * 32 + g * 8);

    s16x8 ones;
    #pragma unroll
    for (int i = 0; i < 8; ++i) ones[i] = (short)0x3F80;

    f32x4 o[4];
    #pragma unroll
    for (int df = 0; df < 4; ++df) o[df] = (f32x4)(0.0f);
    f32x4 l_acc = (f32x4)(0.0f);

    // staging: K 512 chunks (16B), V 512 chunks; 1 round of 512 threads
    const int krow = tid >> 3, kcc = tid & 7;
    const size_t kgo = (size_t)krow * DK + kcc * 8;
    const int    lwk = krow * 64 + ((kcc ^ (krow & 7)) * 8);
    const size_t vgo = (size_t)krow * SEQ + kcc * 8;   // vrow==krow, vcc==kcc
    const int    lwv = krow * 64 + ((kcc ^ (krow & 7)) * 8);

    // prologue: tile 0 -> regs
    s16x8 kr = *(const s16x8*)(Kp + kgo);
    s16x8 vr = *(const s16x8*)(Vp + vgo);

    int cur = 0;
    for (int t0 = 0; t0 < SEQ; t0 += KVT) {
        short* kb = Kbuf[cur];
        short* vb = Vbuf[cur];
        *(s16x8*)(&kb[lwk]) = kr;
        *(s16x8*)(&vb[lwv]) = vr;
        if (t0 + KVT < SEQ) {              // prefetch next tile under compute
            kr = *(const s16x8*)(Kp + (size_t)(t0 + KVT) * DK + kgo);
            vr = *(const s16x8*)(Vp + vgo + t0 + KVT);
        }
        // one asm block = compiler fence on BOTH sides of s_barrier;
        // vmcnt (global prefetch) deliberately NOT drained.
        asm volatile("s_waitcnt lgkmcnt(0)\n\ts_barrier" ::: "memory");
        __builtin_amdgcn_sched_barrier(0);

        // ---- S^T = K . Q^T - MBIAS  (4 tf x 2 k-halves = 8 MFMA) ----
        f32x4 s[4];
        #pragma unroll
        for (int tf = 0; tf < 4; ++tf) s[tf] = (f32x4)(-MBIAS);
        __builtin_amdgcn_s_setprio(1);
        #pragma unroll
        for (int tf = 0; tf < 4; ++tf) {
            const short* krp = &kb[(tf * 16 + r) * 64];
            s16x8 ka0 = *(const s16x8*)(krp + ((g ^ (r & 7)) * 8));
            s16x8 ka1 = *(const s16x8*)(krp + (((4 | g) ^ (r & 7)) * 8));
            s[tf] = __builtin_amdgcn_mfma_f32_16x16x32_bf16(ka0, qfr[0], s[tf], 0, 0, 0);
            s[tf] = __builtin_amdgcn_mfma_f32_16x16x32_bf16(ka1, qfr[1], s[tf], 0, 0, 0);
        }
        __builtin_amdgcn_s_setprio(0);

        // ---- static-max softmax: p = exp2(s), branchless ----
        #pragma unroll
        for (int tf = 0; tf < 4; ++tf) {
            s[tf][0] = fexp2(s[tf][0]);
            s[tf][1] = fexp2(s[tf][1]);
            s[tf][2] = fexp2(s[tf][2]);
            s[tf][3] = fexp2(s[tf][3]);
        }

        // ---- P -> bf16 B-fragments in-register (2 k-halves) ----
        s16x8 pb[2];
        #pragma unroll
        for (int h = 0; h < 2; ++h) {
            int A0 = cvtpk(s[2 * h][0],     s[2 * h][1]);
            int A1 = cvtpk(s[2 * h][2],     s[2 * h][3]);
            int A2 = cvtpk(s[2 * h + 1][0], s[2 * h + 1][1]);
            int A3 = cvtpk(s[2 * h + 1][2], s[2 * h + 1][3]);
            swap32(A0, A2); swap16(A0, A2);
            swap32(A1, A3); swap16(A1, A3);
            i32x4 w; w[0] = A0; w[1] = A1; w[2] = A2; w[3] = A3;
            pb[h] = __builtin_bit_cast(s16x8, w);
        }

        // ---- ctx^T += Vt . P^T ; l += 1 . P^T  (10 MFMA) ----
        __builtin_amdgcn_s_setprio(1);
        #pragma unroll
        for (int h = 0; h < 2; ++h)
            l_acc = __builtin_amdgcn_mfma_f32_16x16x32_bf16(ones, pb[h], l_acc, 0, 0, 0);
        #pragma unroll
        for (int df = 0; df < 4; ++df) {
            const short* vrp = &vb[(df * 16 + r) * 64];
            #pragma unroll
            for (int h = 0; h < 2; ++h) {
                s16x8 va = *(const s16x8*)(vrp + (((h * 4 + g) ^ (r & 7)) * 8));
                o[df] = __builtin_amdgcn_mfma_f32_16x16x32_bf16(va, pb[h], o[df], 0, 0, 0);
            }
        }
        __builtin_amdgcn_s_setprio(0);

        cur ^= 1;
    }

    // ---- epilogue: l lane-local in l_acc[0] ----
    const int b = bh >> 3, h2 = bh & 7;
    {
        const float inv = 1.0f / l_acc[0];
        const int q = q0 + r;
        const size_t rowoff = (size_t)(b * SEQ + q) * DM + h2 * DK;
        #pragma unroll
        for (int df = 0; df < 4; ++df) {
            u16x4 pk;
            #pragma unroll
            for (int i = 0; i < 4; ++i) pk[i] = f2bf(o[df][i] * inv);
            *(u16x4*)(&Ctx[rowoff + df * 16 + g * 4]) = pk;
        }
    }
}

// ---------------------------------------------------------------------------
extern "C" void kernel_launch(void* const* d_in, const int* in_sizes, int n_in,
                              void* d_out, int out_size, void* d_ws, size_t ws_size,
                              hipStream_t stream)
{
    const float* q  = (const float*)d_in[0];
    const float* k  = (const float*)d_in[1];
    const float* v  = (const float*)d_in[2];
    const float* Wq = (const float*)d_in[3];
    const float* bq = (const float*)d_in[4];
    const float* Wk = (const float*)d_in[5];
    const float* bk = (const float*)d_in[6];
    const float* Wv = (const float*)d_in[7];
    const float* bv = (const float*)d_in[8];
    const float* Wo = (const float*)d_in[9];
    const float* bo = (const float*)d_in[10];

    const size_t NE = (size_t)MROWS * DM;            // 4.19M elems per buffer
    unsigned short* ws  = (unsigned short*)d_ws;
    unsigned short* Qw  = ws;                        // [B,H,S,64] bf16, pre-scaled
    unsigned short* Kw  = Qw  + NE;                  // [B,H,S,64] bf16
    unsigned short* Vtw = Kw  + NE;                  // [B,H,64,S] bf16
    unsigned short* Ctx = Vtw + NE;                  // [B*S, 512] bf16
    unsigned short* Wb  = Ctx + NE;                  // 4 x [512,512] bf16

    convert_w<<<512, 256, 0, stream>>>(Wq, Wk, Wv, Wo, Wb);
    dim3 gg3(MROWS / 128, DM / 128, 3);              // (64, 4, 3) = 768 blocks
    gemm_proj3<<<gg3, 256, 0, stream>>>(q, k, v, Wb, bq, bk, bv, Qw, Kw, Vtw);
    attn_kernel<<<512, 512, 0, stream>>>(Qw, Kw, Vtw, Ctx);
    dim3 ggo(MROWS / 64, DM / 128);                  // (128, 4) = 512 blocks
    gemm_out<<<ggo, 256, 0, stream>>>(Ctx, Wb + (size_t)3 * DM * DM, bo, (float*)d_out);
}

// Round 17
// 139.263 us; speedup vs baseline: 1.1008x; 1.0681x over previous
//
#include <hip/hip_runtime.h>

// ---------------------------------------------------------------------------
// MultiHeadAttention  B=2,S=4096,D=512,H=8,dk=64 — bf16 MFMA pipeline.
//   0) convert_w: Wq,Wk,Wv,Wo f32 -> bf16 once
//   1) gemm_proj3 (grid.z=3): dbuf+prefetch+fused-barrier pipeline (R13)
//   2) attn_kernel (R13 structure restored): 8 waves x 16 q-rows, KV tile
//      128, static-max softmax (MBIAS in acc init), l via ones-row MFMA,
//      dbuf + reg-prefetch + fused lgkmcnt+barrier. NEW: V-fragment reads
//      for df=0,1 hoisted before exp/pack (latency hides under softmax).
//   3) gemm_out (64x128 tile): dbuf pipeline -> fp32 out
// ---------------------------------------------------------------------------

#define DM   512
#define NH   8
#define DK   64
#define SEQ  4096
#define BATCH 2
#define MROWS (BATCH*SEQ)
#define KVT  128                    // keys per tile
#define CSC  0.18033688011112042f   // log2(e)/sqrt(64)
#define MBIAS 12.0f                 // static softmax bias (exp2 domain)

typedef __attribute__((ext_vector_type(4))) float  f32x4;
typedef __attribute__((ext_vector_type(8))) short  s16x8;
typedef __attribute__((ext_vector_type(4))) short  s16x4;
typedef __attribute__((ext_vector_type(4))) unsigned short u16x4;
typedef __attribute__((ext_vector_type(4))) int    i32x4;
typedef __attribute__((ext_vector_type(2))) int    i32x2;

static __device__ __forceinline__ unsigned short f2bf(float f) {
    union { float f; unsigned int u; } a; a.f = f;
    unsigned int r = a.u + 0x7FFFu + ((a.u >> 16) & 1u);   // RNE
    return (unsigned short)(r >> 16);
}
static __device__ __forceinline__ int cvtpk(float lo, float hi) {
    int r;
    asm("v_cvt_pk_bf16_f32 %0, %1, %2" : "=v"(r) : "v"(lo), "v"(hi));
    return r;
}
static __device__ __forceinline__ float fexp2(float x) {
    float r;
    asm("v_exp_f32 %0, %1" : "=v"(r) : "v"(x));
    return r;
}
// Safe ONLY with DISTINCT a/b values (two live registers). permlane*_swap(x,x)
// on one SSA value can degenerate to an in-place row permutation (R6/R7 bug).
static __device__ __forceinline__ void swap32(int &a, int &b) {
    auto t = __builtin_amdgcn_permlane32_swap(a, b, false, false);
    a = t[0]; b = t[1];
}
static __device__ __forceinline__ void swap16(int &a, int &b) {
    auto t = __builtin_amdgcn_permlane16_swap(a, b, false, false);
    a = t[0]; b = t[1];
}

// ---------------------------------------------------------------------------
// Weight pre-conversion: 4 x (512x512) f32 -> bf16.
// ---------------------------------------------------------------------------
__global__ __launch_bounds__(256)
void convert_w(const float* __restrict__ W0, const float* __restrict__ W1,
               const float* __restrict__ W2, const float* __restrict__ W3,
               unsigned short* __restrict__ O)
{
    const int idx   = blockIdx.x * 256 + threadIdx.x;   // 131072 threads
    const int which = idx >> 15;                        // 32768 chunks per W
    const int off   = (idx & 32767) * 8;
    const float* W = (which == 0) ? W0 : (which == 1) ? W1 : (which == 2) ? W2 : W3;
    f32x4 a = *(const f32x4*)(W + off);
    f32x4 b = *(const f32x4*)(W + off + 4);
    i32x4 pk;
    pk[0] = cvtpk(a[0], a[1]); pk[1] = cvtpk(a[2], a[3]);
    pk[2] = cvtpk(b[0], b[1]); pk[3] = cvtpk(b[2], b[3]);
    *(i32x4*)(O + (size_t)which * (DM * DM) + off) = pk;
}

// ---------------------------------------------------------------------------
// Fused input projections: z=0 Q (pre-scaled CSC), z=1 K, z=2 V (transposed).
// 128x128 tile, BK=32, 4 waves 2x2. Double-buffered LDS + reg-prefetch +
// ONE fused {lgkmcnt(0); s_barrier} per k-step.  (Frozen R13.)
// ---------------------------------------------------------------------------
__global__ __launch_bounds__(256)
void gemm_proj3(const float* __restrict__ a0, const float* __restrict__ a1,
                const float* __restrict__ a2,
                const unsigned short* __restrict__ Wb,   // 3 x DM*DM bf16
                const float* __restrict__ b0, const float* __restrict__ b1,
                const float* __restrict__ b2,
                unsigned short* __restrict__ O0, unsigned short* __restrict__ O1,
                unsigned short* __restrict__ O2)
{
    __shared__ short As[2][128 * 40];
    __shared__ short Bs[2][128 * 40];

    const int z = blockIdx.z;
    const float* A   = (z == 0) ? a0 : (z == 1) ? a1 : a2;
    const short* W   = (const short*)Wb + (size_t)z * DM * DM;
    const float* bias= (z == 0) ? b0 : (z == 1) ? b1 : b2;
    unsigned short* O= (z == 0) ? O0 : (z == 1) ? O1 : O2;
    const float oscale = (z == 0) ? CSC : 1.0f;
    const bool  vt = (z == 2);

    const int tid  = threadIdx.x;
    const int lane = tid & 63;
    const int wid  = tid >> 6;
    const int g = lane >> 4, r = lane & 15;
    const int wm = wid >> 1, wn = wid & 1;
    const int brow = blockIdx.x * 128;
    const int bcol = blockIdx.y * 128;

    const float* agp[4]; int alw[4];
    #pragma unroll
    for (int j = 0; j < 4; ++j) {
        int c = tid + 256 * j;
        int row = c >> 3, cc = c & 7;
        agp[j] = A + (size_t)(brow + row) * DM + cc * 4;
        alw[j] = row * 40 + cc * 4;
    }
    const short* wgp[2]; int wlw[2];
    #pragma unroll
    for (int j = 0; j < 2; ++j) {
        int c = tid + 256 * j;
        int row = c >> 2, cc = c & 3;
        wgp[j] = W + (size_t)(bcol + row) * DM + cc * 8;
        wlw[j] = row * 40 + cc * 8;
    }

    f32x4 acc[4][4];
    #pragma unroll
    for (int i = 0; i < 4; ++i)
        #pragma unroll
        for (int j = 0; j < 4; ++j) acc[i][j] = (f32x4)(0.0f);

    f32x4 ar[4]; s16x8 wr[2];
    #pragma unroll
    for (int j = 0; j < 4; ++j) ar[j] = *(const f32x4*)(agp[j]);
    #pragma unroll
    for (int j = 0; j < 2; ++j) wr[j] = *(const s16x8*)(wgp[j]);

    int cur = 0;
    for (int k0 = 0; k0 < DM; k0 += 32) {
        short* as = As[cur];
        short* bs = Bs[cur];
        #pragma unroll
        for (int j = 0; j < 4; ++j) {
            i32x2 pk;
            pk[0] = cvtpk(ar[j][0], ar[j][1]);
            pk[1] = cvtpk(ar[j][2], ar[j][3]);
            *(i32x2*)(&as[alw[j]]) = pk;
        }
        #pragma unroll
        for (int j = 0; j < 2; ++j) *(s16x8*)(&bs[wlw[j]]) = wr[j];
        if (k0 + 32 < DM) {
            #pragma unroll
            for (int j = 0; j < 4; ++j) ar[j] = *(const f32x4*)(agp[j] + k0 + 32);
            #pragma unroll
            for (int j = 0; j < 2; ++j) wr[j] = *(const s16x8*)(wgp[j] + k0 + 32);
        }
        asm volatile("s_waitcnt lgkmcnt(0)\n\ts_barrier" ::: "memory");
        __builtin_amdgcn_sched_barrier(0);

        s16x8 af[4], bfr[4];
        #pragma unroll
        for (int mf = 0; mf < 4; ++mf)
            af[mf] = *(const s16x8*)(&as[(wm * 64 + mf * 16 + r) * 40 + g * 8]);
        #pragma unroll
        for (int nf = 0; nf < 4; ++nf)
            bfr[nf] = *(const s16x8*)(&bs[(wn * 64 + nf * 16 + r) * 40 + g * 8]);
        #pragma unroll
        for (int mf = 0; mf < 4; ++mf)
            #pragma unroll
            for (int nf = 0; nf < 4; ++nf)
                acc[mf][nf] = __builtin_amdgcn_mfma_f32_16x16x32_bf16(
                    af[mf], bfr[nf], acc[mf][nf], 0, 0, 0);
        cur ^= 1;
    }

    const int ncolbase = bcol + wn * 64;
    const int mrowbase = brow + wm * 64;
    #pragma unroll
    for (int mf = 0; mf < 4; ++mf) {
        #pragma unroll
        for (int nf = 0; nf < 4; ++nf) {
            const int ncol = ncolbase + nf * 16 + r;
            const int m0   = mrowbase + mf * 16 + g * 4;
            const float bv = bias[ncol];
            const int h = ncol >> 6, d = ncol & 63;
            if (!vt) {
                #pragma unroll
                for (int i = 0; i < 4; ++i) {
                    int m = m0 + i;
                    int b = m >> 12, s = m & (SEQ - 1);
                    O[((size_t)(b * NH + h) * SEQ + s) * DK + d] =
                        f2bf((acc[mf][nf][i] + bv) * oscale);
                }
            } else {
                const int b = m0 >> 12, s0 = m0 & (SEQ - 1);
                u16x4 pk;
                #pragma unroll
                for (int i = 0; i < 4; ++i) pk[i] = f2bf(acc[mf][nf][i] + bv);
                *(u16x4*)(&O[((size_t)(b * NH + h) * DK + d) * SEQ + s0]) = pk;
            }
        }
    }
}

// ---------------------------------------------------------------------------
// Output projection: 64x128 tile, dbuf + prefetch + single-barrier pipeline.
// ---------------------------------------------------------------------------
__global__ __launch_bounds__(256)
void gemm_out(const unsigned short* __restrict__ Ctx,
              const unsigned short* __restrict__ Wb,
              const float* __restrict__ bias,
              float* __restrict__ O)
{
    __shared__ short As[2][64 * 40];
    __shared__ short Bs[2][128 * 40];

    const int tid  = threadIdx.x;
    const int lane = tid & 63;
    const int wid  = tid >> 6;
    const int g = lane >> 4, r = lane & 15;
    const int wm = wid >> 1, wn = wid & 1;
    const int brow = blockIdx.x * 64;
    const int bcol = blockIdx.y * 128;
    const short* W = (const short*)Wb;

    const short* agp; int alw;
    {
        int row = tid >> 2, cc = tid & 3;
        agp = (const short*)Ctx + (size_t)(brow + row) * DM + cc * 8;
        alw = row * 40 + cc * 8;
    }
    const short* wgp[2]; int wlw[2];
    #pragma unroll
    for (int j = 0; j < 2; ++j) {
        int c = tid + 256 * j;
        int row = c >> 2, cc = c & 3;
        wgp[j] = W + (size_t)(bcol + row) * DM + cc * 8;
        wlw[j] = row * 40 + cc * 8;
    }

    f32x4 acc[2][4];
    #pragma unroll
    for (int i = 0; i < 2; ++i)
        #pragma unroll
        for (int j = 0; j < 4; ++j) acc[i][j] = (f32x4)(0.0f);

    s16x8 ar; s16x8 wr[2];
    ar = *(const s16x8*)agp;
    #pragma unroll
    for (int j = 0; j < 2; ++j) wr[j] = *(const s16x8*)(wgp[j]);

    int cur = 0;
    for (int k0 = 0; k0 < DM; k0 += 32) {
        short* as = As[cur];
        short* bs = Bs[cur];
        *(s16x8*)(&as[alw]) = ar;
        #pragma unroll
        for (int j = 0; j < 2; ++j) *(s16x8*)(&bs[wlw[j]]) = wr[j];
        if (k0 + 32 < DM) {
            ar = *(const s16x8*)(agp + k0 + 32);
            #pragma unroll
            for (int j = 0; j < 2; ++j) wr[j] = *(const s16x8*)(wgp[j] + k0 + 32);
        }
        asm volatile("s_waitcnt lgkmcnt(0)\n\ts_barrier" ::: "memory");
        __builtin_amdgcn_sched_barrier(0);

        s16x8 af[2], bfr[4];
        #pragma unroll
        for (int mf = 0; mf < 2; ++mf)
            af[mf] = *(const s16x8*)(&as[(wm * 32 + mf * 16 + r) * 40 + g * 8]);
        #pragma unroll
        for (int nf = 0; nf < 4; ++nf)
            bfr[nf] = *(const s16x8*)(&bs[(wn * 64 + nf * 16 + r) * 40 + g * 8]);
        #pragma unroll
        for (int mf = 0; mf < 2; ++mf)
            #pragma unroll
            for (int nf = 0; nf < 4; ++nf)
                acc[mf][nf] = __builtin_amdgcn_mfma_f32_16x16x32_bf16(
                    af[mf], bfr[nf], acc[mf][nf], 0, 0, 0);
        cur ^= 1;
    }

    const int ncolbase = bcol + wn * 64;
    const int mrowbase = brow + wm * 32;
    #pragma unroll
    for (int mf = 0; mf < 2; ++mf) {
        #pragma unroll
        for (int nf = 0; nf < 4; ++nf) {
            const int ncol = ncolbase + nf * 16 + r;
            const int m0   = mrowbase + mf * 16 + g * 4;
            const float bv = bias[ncol];
            #pragma unroll
            for (int i = 0; i < 4; ++i)
                O[(size_t)(m0 + i) * DM + ncol] = acc[mf][nf][i] + bv;
        }
    }
}

// ---------------------------------------------------------------------------
// Flash attention (R13 structure): 8 waves x 16 q-rows (512 thr), KV tile 128.
//   S^T  = mfma(A=K[t,d],  B=Q[q,d])  -> C[t,q], col(lane&15)=q
//   ctx^T= mfma(A=Vt[d,t], B=P[q,t])  -> C[d,q], col(lane&15)=q
// Static-max softmax (MBIAS in acc init); l via ones-row MFMA.
// R17 micro-opt: V-fragment LDS reads for df=0,1 issued BEFORE exp/pack so
// their latency hides under the softmax chain (+32 VGPR, ~92 total, still
// 4 waves/SIMD under __launch_bounds__(512,4)).
// ---------------------------------------------------------------------------
__global__ __launch_bounds__(512, 4)
void attn_kernel(const unsigned short* __restrict__ Qw,
                 const unsigned short* __restrict__ Kw,
                 const unsigned short* __restrict__ Vtw,
                 unsigned short* __restrict__ Ctx)
{
    __shared__ short Kbuf[2][KVT * 64];
    __shared__ short Vbuf[2][64 * KVT];

    const int tid  = threadIdx.x;
    const int lane = tid & 63;
    const int wid  = tid >> 6;            // 0..7
    const int g = lane >> 4, r = lane & 15;

    const int B   = blockIdx.x;            // 0..511
    const int xcd = B & 7;
    const int j   = B >> 3;                // 0..63
    const int bh  = xcd * 2 + (j >> 5);    // 2 bh per XCD
    const int qt  = j & 31;
    const int q0  = qt * 128 + wid * 16;   // wave owns 16 q-rows

    const short* Qp = (const short*)Qw  + (size_t)bh * SEQ * DK;
    const short* Kp = (const short*)Kw  + (size_t)bh * SEQ * DK;
    const short* Vp = (const short*)Vtw + (size_t)bh * DK * SEQ;

    s16x8 qfr[2];
    #pragma unroll
    for (int df = 0; df < 2; ++df)
        qfr[df] = *(const s16x8*)(Qp + (size_t)(q0 + r) * DK + df * 32 + g * 8);

    s16x8 ones;
    #pragma unroll
    for (int i = 0; i < 8; ++i) ones[i] = (short)0x3F80;

    f32x4 o[4];
    #pragma unroll
    for (int df = 0; df < 4; ++df) o[df] = (f32x4)(0.0f);
    f32x4 l_acc = (f32x4)(0.0f);

    // staging: K 1024 chunks (16B), V 1024 chunks; 2 rounds of 512 threads
    int    lwk[2], lwv[2];
    size_t kgo[2], vgo[2];
    #pragma unroll
    for (int jj = 0; jj < 2; ++jj) {
        int c = tid + 512 * jj;
        int krow = c >> 3, kcc = c & 7;
        kgo[jj] = (size_t)krow * DK + kcc * 8;
        lwk[jj] = krow * 64 + ((kcc ^ (krow & 7)) * 8);
        int vrow = c >> 4, vcc = c & 15;
        vgo[jj] = (size_t)vrow * SEQ + vcc * 8;
        lwv[jj] = vrow * KVT + ((vcc ^ (vrow & 15)) * 8);
    }

    s16x8 kr[2], vr[2];
    #pragma unroll
    for (int jj = 0; jj < 2; ++jj) {
        kr[jj] = *(const s16x8*)(Kp + kgo[jj]);
        vr[jj] = *(const s16x8*)(Vp + vgo[jj]);
    }

    int cur = 0;
    for (int t0 = 0; t0 < SEQ; t0 += KVT) {
        short* kb = Kbuf[cur];
        short* vb = Vbuf[cur];
        #pragma unroll
        for (int jj = 0; jj < 2; ++jj) {
            *(s16x8*)(&kb[lwk[jj]]) = kr[jj];
            *(s16x8*)(&vb[lwv[jj]]) = vr[jj];
        }
        if (t0 + KVT < SEQ) {              // prefetch next tile under compute
            #pragma unroll
            for (int jj = 0; jj < 2; ++jj) {
                kr[jj] = *(const s16x8*)(Kp + (size_t)(t0 + KVT) * DK + kgo[jj]);
                vr[jj] = *(const s16x8*)(Vp + vgo[jj] + t0 + KVT);
            }
        }
        asm volatile("s_waitcnt lgkmcnt(0)\n\ts_barrier" ::: "memory");
        __builtin_amdgcn_sched_barrier(0);

        // ---- S^T = K . Q^T - MBIAS ----
        f32x4 s[8];
        #pragma unroll
        for (int tf = 0; tf < 8; ++tf) s[tf] = (f32x4)(-MBIAS);
        __builtin_amdgcn_s_setprio(1);
        #pragma unroll
        for (int tf = 0; tf < 8; ++tf) {
            const short* krow = &kb[(tf * 16 + r) * 64];
            s16x8 ka0 = *(const s16x8*)(krow + ((g ^ (r & 7)) * 8));
            s16x8 ka1 = *(const s16x8*)(krow + (((4 | g) ^ (r & 7)) * 8));
            s[tf] = __builtin_amdgcn_mfma_f32_16x16x32_bf16(ka0, qfr[0], s[tf], 0, 0, 0);
            s[tf] = __builtin_amdgcn_mfma_f32_16x16x32_bf16(ka1, qfr[1], s[tf], 0, 0, 0);
        }
        __builtin_amdgcn_s_setprio(0);

        // ---- R17: issue V reads for df=0,1 EARLY (hide under exp/pack) ----
        s16x8 va01[8];
        #pragma unroll
        for (int df = 0; df < 2; ++df) {
            const short* vrow = &vb[(df * 16 + r) * KVT];
            #pragma unroll
            for (int h = 0; h < 4; ++h)
                va01[df * 4 + h] = *(const s16x8*)(vrow + (((h * 4 + g) ^ r) * 8));
        }

        // ---- static-max softmax: p = exp2(s) ----
        #pragma unroll
        for (int tf = 0; tf < 8; ++tf) {
            s[tf][0] = fexp2(s[tf][0]);
            s[tf][1] = fexp2(s[tf][1]);
            s[tf][2] = fexp2(s[tf][2]);
            s[tf][3] = fexp2(s[tf][3]);
        }

        // ---- P -> bf16 B-fragments in-register ----
        s16x8 pb[4];
        #pragma unroll
        for (int h = 0; h < 4; ++h) {
            int A0 = cvtpk(s[2 * h][0],     s[2 * h][1]);
            int A1 = cvtpk(s[2 * h][2],     s[2 * h][3]);
            int A2 = cvtpk(s[2 * h + 1][0], s[2 * h + 1][1]);
            int A3 = cvtpk(s[2 * h + 1][2], s[2 * h + 1][3]);
            swap32(A0, A2); swap16(A0, A2);
            swap32(A1, A3); swap16(A1, A3);
            i32x4 w; w[0] = A0; w[1] = A1; w[2] = A2; w[3] = A3;
            pb[h] = __builtin_bit_cast(s16x8, w);
        }

        // ---- ctx^T += Vt . P^T ; l += 1 . P^T ----
        __builtin_amdgcn_s_setprio(1);
        #pragma unroll
        for (int h = 0; h < 4; ++h)
            l_acc = __builtin_amdgcn_mfma_f32_16x16x32_bf16(ones, pb[h], l_acc, 0, 0, 0);
        #pragma unroll
        for (int df = 0; df < 2; ++df)
            #pragma unroll
            for (int h = 0; h < 4; ++h)
                o[df] = __builtin_amdgcn_mfma_f32_16x16x32_bf16(va01[df * 4 + h], pb[h], o[df], 0, 0, 0);
        #pragma unroll
        for (int df = 2; df < 4; ++df) {
            const short* vrow = &vb[(df * 16 + r) * KVT];
            #pragma unroll
            for (int h = 0; h < 4; ++h) {
                s16x8 va = *(const s16x8*)(vrow + (((h * 4 + g) ^ r) * 8));
                o[df] = __builtin_amdgcn_mfma_f32_16x16x32_bf16(va, pb[h], o[df], 0, 0, 0);
            }
        }
        __builtin_amdgcn_s_setprio(0);

        cur ^= 1;
    }

    // ---- epilogue: l lane-local in l_acc[0] ----
    const int b = bh >> 3, h2 = bh & 7;
    {
        const float inv = 1.0f / l_acc[0];
        const int q = q0 + r;
        const size_t rowoff = (size_t)(b * SEQ + q) * DM + h2 * DK;
        #pragma unroll
        for (int df = 0; df < 4; ++df) {
            u16x4 pk;
            #pragma unroll
            for (int i = 0; i < 4; ++i) pk[i] = f2bf(o[df][i] * inv);
            *(u16x4*)(&Ctx[rowoff + df * 16 + g * 4]) = pk;
        }
    }
}

// ---------------------------------------------------------------------------
extern "C" void kernel_launch(void* const* d_in, const int* in_sizes, int n_in,
                              void* d_out, int out_size, void* d_ws, size_t ws_size,
                              hipStream_t stream)
{
    const float* q  = (const float*)d_in[0];
    const float* k  = (const float*)d_in[1];
    const float* v  = (const float*)d_in[2];
    const float* Wq = (const float*)d_in[3];
    const float* bq = (const float*)d_in[4];
    const float* Wk = (const float*)d_in[5];
    const float* bk = (const float*)d_in[6];
    const float* Wv = (const float*)d_in[7];
    const float* bv = (const float*)d_in[8];
    const float* Wo = (const float*)d_in[9];
    const float* bo = (const float*)d_in[10];

    const size_t NE = (size_t)MROWS * DM;            // 4.19M elems per buffer
    unsigned short* ws  = (unsigned short*)d_ws;
    unsigned short* Qw  = ws;                        // [B,H,S,64] bf16, pre-scaled
    unsigned short* Kw  = Qw  + NE;                  // [B,H,S,64] bf16
    unsigned short* Vtw = Kw  + NE;                  // [B,H,64,S] bf16
    unsigned short* Ctx = Vtw + NE;                  // [B*S, 512] bf16
    unsigned short* Wb  = Ctx + NE;                  // 4 x [512,512] bf16

    convert_w<<<512, 256, 0, stream>>>(Wq, Wk, Wv, Wo, Wb);
    dim3 gg3(MROWS / 128, DM / 128, 3);              // (64, 4, 3) = 768 blocks
    gemm_proj3<<<gg3, 256, 0, stream>>>(q, k, v, Wb, bq, bk, bv, Qw, Kw, Vtw);
    attn_kernel<<<512, 512, 0, stream>>>(Qw, Kw, Vtw, Ctx);
    dim3 ggo(MROWS / 64, DM / 128);                  // (128, 4) = 512 blocks
    gemm_out<<<ggo, 256, 0, stream>>>(Ctx, Wb + (size_t)3 * DM * DM, bo, (float*)d_out);
}

// Round 18
// 124.276 us; speedup vs baseline: 1.2336x; 1.1206x over previous
//
#include <hip/hip_runtime.h>

// ---------------------------------------------------------------------------
// MultiHeadAttention  B=2,S=4096,D=512,H=8,dk=64 — bf16 MFMA pipeline.
//   0) convert_w: Wq,Wk,Wv,Wo f32 -> bf16 once
//   1) gemm_proj3 (grid.z=3): dbuf+prefetch+fused-barrier pipeline
//   2) attn_kernel: 8 waves x 16 q-rows, KV tile 128, static-max softmax
//      (MBIAS folded into MFMA acc init), l via ones-row MFMA.
//      (R13-proven best: 88.7us, VGPR 60, no spill.)
//   3) gemm_out (64x128 tile): dbuf pipeline -> fp32 out
// ---------------------------------------------------------------------------

#define DM   512
#define NH   8
#define DK   64
#define SEQ  4096
#define BATCH 2
#define MROWS (BATCH*SEQ)
#define KVT  128                    // keys per tile
#define CSC  0.18033688011112042f   // log2(e)/sqrt(64)
#define MBIAS 12.0f                 // static softmax bias (exp2 domain)

typedef __attribute__((ext_vector_type(4))) float  f32x4;
typedef __attribute__((ext_vector_type(8))) short  s16x8;
typedef __attribute__((ext_vector_type(4))) short  s16x4;
typedef __attribute__((ext_vector_type(4))) unsigned short u16x4;
typedef __attribute__((ext_vector_type(4))) int    i32x4;
typedef __attribute__((ext_vector_type(2))) int    i32x2;

static __device__ __forceinline__ unsigned short f2bf(float f) {
    union { float f; unsigned int u; } a; a.f = f;
    unsigned int r = a.u + 0x7FFFu + ((a.u >> 16) & 1u);   // RNE
    return (unsigned short)(r >> 16);
}
static __device__ __forceinline__ int cvtpk(float lo, float hi) {
    int r;
    asm("v_cvt_pk_bf16_f32 %0, %1, %2" : "=v"(r) : "v"(lo), "v"(hi));
    return r;
}
static __device__ __forceinline__ float fexp2(float x) {
    float r;
    asm("v_exp_f32 %0, %1" : "=v"(r) : "v"(x));
    return r;
}
// Safe ONLY with DISTINCT a/b values (two live registers). permlane*_swap(x,x)
// on one SSA value can degenerate to an in-place row permutation (R6/R7 bug).
static __device__ __forceinline__ void swap32(int &a, int &b) {
    auto t = __builtin_amdgcn_permlane32_swap(a, b, false, false);
    a = t[0]; b = t[1];
}
static __device__ __forceinline__ void swap16(int &a, int &b) {
    auto t = __builtin_amdgcn_permlane16_swap(a, b, false, false);
    a = t[0]; b = t[1];
}

// ---------------------------------------------------------------------------
// Weight pre-conversion: 4 x (512x512) f32 -> bf16.
// ---------------------------------------------------------------------------
__global__ __launch_bounds__(256)
void convert_w(const float* __restrict__ W0, const float* __restrict__ W1,
               const float* __restrict__ W2, const float* __restrict__ W3,
               unsigned short* __restrict__ O)
{
    const int idx   = blockIdx.x * 256 + threadIdx.x;   // 131072 threads
    const int which = idx >> 15;                        // 32768 chunks per W
    const int off   = (idx & 32767) * 8;
    const float* W = (which == 0) ? W0 : (which == 1) ? W1 : (which == 2) ? W2 : W3;
    f32x4 a = *(const f32x4*)(W + off);
    f32x4 b = *(const f32x4*)(W + off + 4);
    i32x4 pk;
    pk[0] = cvtpk(a[0], a[1]); pk[1] = cvtpk(a[2], a[3]);
    pk[2] = cvtpk(b[0], b[1]); pk[3] = cvtpk(b[2], b[3]);
    *(i32x4*)(O + (size_t)which * (DM * DM) + off) = pk;
}

// ---------------------------------------------------------------------------
// Fused input projections: z=0 Q (pre-scaled CSC), z=1 K, z=2 V (transposed).
// 128x128 tile, BK=32, 4 waves 2x2. Double-buffered LDS + reg-prefetch +
// ONE fused {lgkmcnt(0); s_barrier} per k-step.
// ---------------------------------------------------------------------------
__global__ __launch_bounds__(256)
void gemm_proj3(const float* __restrict__ a0, const float* __restrict__ a1,
                const float* __restrict__ a2,
                const unsigned short* __restrict__ Wb,   // 3 x DM*DM bf16
                const float* __restrict__ b0, const float* __restrict__ b1,
                const float* __restrict__ b2,
                unsigned short* __restrict__ O0, unsigned short* __restrict__ O1,
                unsigned short* __restrict__ O2)
{
    __shared__ short As[2][128 * 40];
    __shared__ short Bs[2][128 * 40];

    const int z = blockIdx.z;
    const float* A   = (z == 0) ? a0 : (z == 1) ? a1 : a2;
    const short* W   = (const short*)Wb + (size_t)z * DM * DM;
    const float* bias= (z == 0) ? b0 : (z == 1) ? b1 : b2;
    unsigned short* O= (z == 0) ? O0 : (z == 1) ? O1 : O2;
    const float oscale = (z == 0) ? CSC : 1.0f;
    const bool  vt = (z == 2);

    const int tid  = threadIdx.x;
    const int lane = tid & 63;
    const int wid  = tid >> 6;
    const int g = lane >> 4, r = lane & 15;
    const int wm = wid >> 1, wn = wid & 1;
    const int brow = blockIdx.x * 128;
    const int bcol = blockIdx.y * 128;

    const float* agp[4]; int alw[4];
    #pragma unroll
    for (int j = 0; j < 4; ++j) {
        int c = tid + 256 * j;
        int row = c >> 3, cc = c & 7;
        agp[j] = A + (size_t)(brow + row) * DM + cc * 4;
        alw[j] = row * 40 + cc * 4;
    }
    const short* wgp[2]; int wlw[2];
    #pragma unroll
    for (int j = 0; j < 2; ++j) {
        int c = tid + 256 * j;
        int row = c >> 2, cc = c & 3;
        wgp[j] = W + (size_t)(bcol + row) * DM + cc * 8;
        wlw[j] = row * 40 + cc * 8;
    }

    f32x4 acc[4][4];
    #pragma unroll
    for (int i = 0; i < 4; ++i)
        #pragma unroll
        for (int j = 0; j < 4; ++j) acc[i][j] = (f32x4)(0.0f);

    f32x4 ar[4]; s16x8 wr[2];
    #pragma unroll
    for (int j = 0; j < 4; ++j) ar[j] = *(const f32x4*)(agp[j]);
    #pragma unroll
    for (int j = 0; j < 2; ++j) wr[j] = *(const s16x8*)(wgp[j]);

    int cur = 0;
    for (int k0 = 0; k0 < DM; k0 += 32) {
        short* as = As[cur];
        short* bs = Bs[cur];
        #pragma unroll
        for (int j = 0; j < 4; ++j) {
            i32x2 pk;
            pk[0] = cvtpk(ar[j][0], ar[j][1]);
            pk[1] = cvtpk(ar[j][2], ar[j][3]);
            *(i32x2*)(&as[alw[j]]) = pk;
        }
        #pragma unroll
        for (int j = 0; j < 2; ++j) *(s16x8*)(&bs[wlw[j]]) = wr[j];
        if (k0 + 32 < DM) {
            #pragma unroll
            for (int j = 0; j < 4; ++j) ar[j] = *(const f32x4*)(agp[j] + k0 + 32);
            #pragma unroll
            for (int j = 0; j < 2; ++j) wr[j] = *(const s16x8*)(wgp[j] + k0 + 32);
        }
        asm volatile("s_waitcnt lgkmcnt(0)\n\ts_barrier" ::: "memory");
        __builtin_amdgcn_sched_barrier(0);

        s16x8 af[4], bfr[4];
        #pragma unroll
        for (int mf = 0; mf < 4; ++mf)
            af[mf] = *(const s16x8*)(&as[(wm * 64 + mf * 16 + r) * 40 + g * 8]);
        #pragma unroll
        for (int nf = 0; nf < 4; ++nf)
            bfr[nf] = *(const s16x8*)(&bs[(wn * 64 + nf * 16 + r) * 40 + g * 8]);
        #pragma unroll
        for (int mf = 0; mf < 4; ++mf)
            #pragma unroll
            for (int nf = 0; nf < 4; ++nf)
                acc[mf][nf] = __builtin_amdgcn_mfma_f32_16x16x32_bf16(
                    af[mf], bfr[nf], acc[mf][nf], 0, 0, 0);
        cur ^= 1;
    }

    const int ncolbase = bcol + wn * 64;
    const int mrowbase = brow + wm * 64;
    #pragma unroll
    for (int mf = 0; mf < 4; ++mf) {
        #pragma unroll
        for (int nf = 0; nf < 4; ++nf) {
            const int ncol = ncolbase + nf * 16 + r;
            const int m0   = mrowbase + mf * 16 + g * 4;
            const float bv = bias[ncol];
            const int h = ncol >> 6, d = ncol & 63;
            if (!vt) {
                #pragma unroll
                for (int i = 0; i < 4; ++i) {
                    int m = m0 + i;
                    int b = m >> 12, s = m & (SEQ - 1);
                    O[((size_t)(b * NH + h) * SEQ + s) * DK + d] =
                        f2bf((acc[mf][nf][i] + bv) * oscale);
                }
            } else {
                const int b = m0 >> 12, s0 = m0 & (SEQ - 1);
                u16x4 pk;
                #pragma unroll
                for (int i = 0; i < 4; ++i) pk[i] = f2bf(acc[mf][nf][i] + bv);
                *(u16x4*)(&O[((size_t)(b * NH + h) * DK + d) * SEQ + s0]) = pk;
            }
        }
    }
}

// ---------------------------------------------------------------------------
// Output projection: 64x128 tile, dbuf + prefetch + single-barrier pipeline.
// ---------------------------------------------------------------------------
__global__ __launch_bounds__(256)
void gemm_out(const unsigned short* __restrict__ Ctx,
              const unsigned short* __restrict__ Wb,
              const float* __restrict__ bias,
              float* __restrict__ O)
{
    __shared__ short As[2][64 * 40];
    __shared__ short Bs[2][128 * 40];

    const int tid  = threadIdx.x;
    const int lane = tid & 63;
    const int wid  = tid >> 6;
    const int g = lane >> 4, r = lane & 15;
    const int wm = wid >> 1, wn = wid & 1;
    const int brow = blockIdx.x * 64;
    const int bcol = blockIdx.y * 128;
    const short* W = (const short*)Wb;

    const short* agp; int alw;
    {
        int row = tid >> 2, cc = tid & 3;
        agp = (const short*)Ctx + (size_t)(brow + row) * DM + cc * 8;
        alw = row * 40 + cc * 8;
    }
    const short* wgp[2]; int wlw[2];
    #pragma unroll
    for (int j = 0; j < 2; ++j) {
        int c = tid + 256 * j;
        int row = c >> 2, cc = c & 3;
        wgp[j] = W + (size_t)(bcol + row) * DM + cc * 8;
        wlw[j] = row * 40 + cc * 8;
    }

    f32x4 acc[2][4];
    #pragma unroll
    for (int i = 0; i < 2; ++i)
        #pragma unroll
        for (int j = 0; j < 4; ++j) acc[i][j] = (f32x4)(0.0f);

    s16x8 ar; s16x8 wr[2];
    ar = *(const s16x8*)agp;
    #pragma unroll
    for (int j = 0; j < 2; ++j) wr[j] = *(const s16x8*)(wgp[j]);

    int cur = 0;
    for (int k0 = 0; k0 < DM; k0 += 32) {
        short* as = As[cur];
        short* bs = Bs[cur];
        *(s16x8*)(&as[alw]) = ar;
        #pragma unroll
        for (int j = 0; j < 2; ++j) *(s16x8*)(&bs[wlw[j]]) = wr[j];
        if (k0 + 32 < DM) {
            ar = *(const s16x8*)(agp + k0 + 32);
            #pragma unroll
            for (int j = 0; j < 2; ++j) wr[j] = *(const s16x8*)(wgp[j] + k0 + 32);
        }
        asm volatile("s_waitcnt lgkmcnt(0)\n\ts_barrier" ::: "memory");
        __builtin_amdgcn_sched_barrier(0);

        s16x8 af[2], bfr[4];
        #pragma unroll
        for (int mf = 0; mf < 2; ++mf)
            af[mf] = *(const s16x8*)(&as[(wm * 32 + mf * 16 + r) * 40 + g * 8]);
        #pragma unroll
        for (int nf = 0; nf < 4; ++nf)
            bfr[nf] = *(const s16x8*)(&bs[(wn * 64 + nf * 16 + r) * 40 + g * 8]);
        #pragma unroll
        for (int mf = 0; mf < 2; ++mf)
            #pragma unroll
            for (int nf = 0; nf < 4; ++nf)
                acc[mf][nf] = __builtin_amdgcn_mfma_f32_16x16x32_bf16(
                    af[mf], bfr[nf], acc[mf][nf], 0, 0, 0);
        cur ^= 1;
    }

    const int ncolbase = bcol + wn * 64;
    const int mrowbase = brow + wm * 32;
    #pragma unroll
    for (int mf = 0; mf < 2; ++mf) {
        #pragma unroll
        for (int nf = 0; nf < 4; ++nf) {
            const int ncol = ncolbase + nf * 16 + r;
            const int m0   = mrowbase + mf * 16 + g * 4;
            const float bv = bias[ncol];
            #pragma unroll
            for (int i = 0; i < 4; ++i)
                O[(size_t)(m0 + i) * DM + ncol] = acc[mf][nf][i] + bv;
        }
    }
}

// ---------------------------------------------------------------------------
// Flash attention (R13-proven): 8 waves x 16 q-rows (512 thr), KV tile 128.
//   S^T  = mfma(A=K[t,d],  B=Q[q,d])  -> C[t,q], col(lane&15)=q
//   ctx^T= mfma(A=Vt[d,t], B=P[q,t])  -> C[d,q], col(lane&15)=q
// Static-max softmax (MBIAS in acc init); l via ones-row MFMA.
// ---------------------------------------------------------------------------
__global__ __launch_bounds__(512, 4)
void attn_kernel(const unsigned short* __restrict__ Qw,
                 const unsigned short* __restrict__ Kw,
                 const unsigned short* __restrict__ Vtw,
                 unsigned short* __restrict__ Ctx)
{
    __shared__ short Kbuf[2][KVT * 64];
    __shared__ short Vbuf[2][64 * KVT];

    const int tid  = threadIdx.x;
    const int lane = tid & 63;
    const int wid  = tid >> 6;            // 0..7
    const int g = lane >> 4, r = lane & 15;

    const int B   = blockIdx.x;            // 0..511
    const int xcd = B & 7;
    const int j   = B >> 3;                // 0..63
    const int bh  = xcd * 2 + (j >> 5);    // 2 bh per XCD
    const int qt  = j & 31;
    const int q0  = qt * 128 + wid * 16;   // wave owns 16 q-rows

    const short* Qp = (const short*)Qw  + (size_t)bh * SEQ * DK;
    const short* Kp = (const short*)Kw  + (size_t)bh * SEQ * DK;
    const short* Vp = (const short*)Vtw + (size_t)bh * DK * SEQ;

    s16x8 qfr[2];
    #pragma unroll
    for (int df = 0; df < 2; ++df)
        qfr[df] = *(const s16x8*)(Qp + (size_t)(q0 + r) * DK + df * 32 + g * 8);

    s16x8 ones;
    #pragma unroll
    for (int i = 0; i < 8; ++i) ones[i] = (short)0x3F80;

    f32x4 o[4];
    #pragma unroll
    for (int df = 0; df < 4; ++df) o[df] = (f32x4)(0.0f);
    f32x4 l_acc = (f32x4)(0.0f);

    int    lwk[2], lwv[2];
    size_t kgo[2], vgo[2];
    #pragma unroll
    for (int jj = 0; jj < 2; ++jj) {
        int c = tid + 512 * jj;
        int krow = c >> 3, kcc = c & 7;
        kgo[jj] = (size_t)krow * DK + kcc * 8;
        lwk[jj] = krow * 64 + ((kcc ^ (krow & 7)) * 8);
        int vrow = c >> 4, vcc = c & 15;
        vgo[jj] = (size_t)vrow * SEQ + vcc * 8;
        lwv[jj] = vrow * KVT + ((vcc ^ (vrow & 15)) * 8);
    }

    s16x8 kr[2], vr[2];
    #pragma unroll
    for (int jj = 0; jj < 2; ++jj) {
        kr[jj] = *(const s16x8*)(Kp + kgo[jj]);
        vr[jj] = *(const s16x8*)(Vp + vgo[jj]);
    }

    int cur = 0;
    for (int t0 = 0; t0 < SEQ; t0 += KVT) {
        short* kb = Kbuf[cur];
        short* vb = Vbuf[cur];
        #pragma unroll
        for (int jj = 0; jj < 2; ++jj) {
            *(s16x8*)(&kb[lwk[jj]]) = kr[jj];
            *(s16x8*)(&vb[lwv[jj]]) = vr[jj];
        }
        if (t0 + KVT < SEQ) {              // prefetch next tile under compute
            #pragma unroll
            for (int jj = 0; jj < 2; ++jj) {
                kr[jj] = *(const s16x8*)(Kp + (size_t)(t0 + KVT) * DK + kgo[jj]);
                vr[jj] = *(const s16x8*)(Vp + vgo[jj] + t0 + KVT);
            }
        }
        asm volatile("s_waitcnt lgkmcnt(0)\n\ts_barrier" ::: "memory");
        __builtin_amdgcn_sched_barrier(0);

        // ---- S^T = K . Q^T - MBIAS ----
        f32x4 s[8];
        #pragma unroll
        for (int tf = 0; tf < 8; ++tf) s[tf] = (f32x4)(-MBIAS);
        __builtin_amdgcn_s_setprio(1);
        #pragma unroll
        for (int tf = 0; tf < 8; ++tf) {
            const short* krow = &kb[(tf * 16 + r) * 64];
            s16x8 ka0 = *(const s16x8*)(krow + ((g ^ (r & 7)) * 8));
            s16x8 ka1 = *(const s16x8*)(krow + (((4 | g) ^ (r & 7)) * 8));
            s[tf] = __builtin_amdgcn_mfma_f32_16x16x32_bf16(ka0, qfr[0], s[tf], 0, 0, 0);
            s[tf] = __builtin_amdgcn_mfma_f32_16x16x32_bf16(ka1, qfr[1], s[tf], 0, 0, 0);
        }
        __builtin_amdgcn_s_setprio(0);

        // ---- static-max softmax: p = exp2(s) ----
        #pragma unroll
        for (int tf = 0; tf < 8; ++tf) {
            s[tf][0] = fexp2(s[tf][0]);
            s[tf][1] = fexp2(s[tf][1]);
            s[tf][2] = fexp2(s[tf][2]);
            s[tf][3] = fexp2(s[tf][3]);
        }

        // ---- P -> bf16 B-fragments in-register ----
        s16x8 pb[4];
        #pragma unroll
        for (int h = 0; h < 4; ++h) {
            int A0 = cvtpk(s[2 * h][0],     s[2 * h][1]);
            int A1 = cvtpk(s[2 * h][2],     s[2 * h][3]);
            int A2 = cvtpk(s[2 * h + 1][0], s[2 * h + 1][1]);
            int A3 = cvtpk(s[2 * h + 1][2], s[2 * h + 1][3]);
            swap32(A0, A2); swap16(A0, A2);
            swap32(A1, A3); swap16(A1, A3);
            i32x4 w; w[0] = A0; w[1] = A1; w[2] = A2; w[3] = A3;
            pb[h] = __builtin_bit_cast(s16x8, w);
        }

        // ---- ctx^T += Vt . P^T ; l += 1 . P^T ----
        __builtin_amdgcn_s_setprio(1);
        #pragma unroll
        for (int h = 0; h < 4; ++h)
            l_acc = __builtin_amdgcn_mfma_f32_16x16x32_bf16(ones, pb[h], l_acc, 0, 0, 0);
        #pragma unroll
        for (int df = 0; df < 4; ++df) {
            const short* vrow = &vb[(df * 16 + r) * KVT];
            #pragma unroll
            for (int h = 0; h < 4; ++h) {
                s16x8 va = *(const s16x8*)(vrow + (((h * 4 + g) ^ r) * 8));
                o[df] = __builtin_amdgcn_mfma_f32_16x16x32_bf16(va, pb[h], o[df], 0, 0, 0);
            }
        }
        __builtin_amdgcn_s_setprio(0);

        cur ^= 1;
    }

    const int b = bh >> 3, h2 = bh & 7;
    {
        const float inv = 1.0f / l_acc[0];
        const int q = q0 + r;
        const size_t rowoff = (size_t)(b * SEQ + q) * DM + h2 * DK;
        #pragma unroll
        for (int df = 0; df < 4; ++df) {
            u16x4 pk;
            #pragma unroll
            for (int i = 0; i < 4; ++i) pk[i] = f2bf(o[df][i] * inv);
            *(u16x4*)(&Ctx[rowoff + df * 16 + g * 4]) = pk;
        }
    }
}

// ---------------------------------------------------------------------------
extern "C" void kernel_launch(void* const* d_in, const int* in_sizes, int n_in,
                              void* d_out, int out_size, void* d_ws, size_t ws_size,
                              hipStream_t stream)
{
    const float* q  = (const float*)d_in[0];
    const float* k  = (const float*)d_in[1];
    const float* v  = (const float*)d_in[2];
    const float* Wq = (const float*)d_in[3];
    const float* bq = (const float*)d_in[4];
    const float* Wk = (const float*)d_in[5];
    const float* bk = (const float*)d_in[6];
    const float* Wv = (const float*)d_in[7];
    const float* bv = (const float*)d_in[8];
    const float* Wo = (const float*)d_in[9];
    const float* bo = (const float*)d_in[10];

    const size_t NE = (size_t)MROWS * DM;            // 4.19M elems per buffer
    unsigned short* ws  = (unsigned short*)d_ws;
    unsigned short* Qw  = ws;                        // [B,H,S,64] bf16, pre-scaled
    unsigned short* Kw  = Qw  + NE;                  // [B,H,S,64] bf16
    unsigned short* Vtw = Kw  + NE;                  // [B,H,64,S] bf16
    unsigned short* Ctx = Vtw + NE;                  // [B*S, 512] bf16
    unsigned short* Wb  = Ctx + NE;                  // 4 x [512,512] bf16

    convert_w<<<512, 256, 0, stream>>>(Wq, Wk, Wv, Wo, Wb);
    dim3 gg3(MROWS / 128, DM / 128, 3);              // (64, 4, 3) = 768 blocks
    gemm_proj3<<<gg3, 256, 0, stream>>>(q, k, v, Wb, bq, bk, bv, Qw, Kw, Vtw);
    attn_kernel<<<512, 512, 0, stream>>>(Qw, Kw, Vtw, Ctx);
    dim3 ggo(MROWS / 64, DM / 128);                  // (128, 4) = 512 blocks
    gemm_out<<<ggo, 256, 0, stream>>>(Ctx, Wb + (size_t)3 * DM * DM, bo, (float*)d_out);
}